// Round 5
// baseline (632.090 us; speedup 1.0000x reference)
//
#include <hip/hip_runtime.h>
#include <hip/hip_bf16.h>

// fp32 in/out; big GEMMs + KA expert via bf16 MFMA (16x16x32), fp32 accumulate.

__device__ __forceinline__ float u16tof(unsigned short u){
  union { unsigned int i; float f; } v; v.i = ((unsigned int)u) << 16; return v.f;
}
__device__ __forceinline__ unsigned short f2b(float f){   // RNE f32->bf16
  union { float f; unsigned int u; } v; v.f = f;
  unsigned int r = v.u + 0x7fffu + ((v.u >> 16) & 1u);
  return (unsigned short)(r >> 16);
}

// fast exact-gelu: A&S 7.1.26 erf approx, |err|<=1.5e-7, hw exp/rcp
__device__ __forceinline__ float gelu_f(float v){
  float y = fabsf(v) * 0.70710678118654752f;
  float t = __builtin_amdgcn_rcpf(fmaf(0.3275911f, y, 1.0f));
  float p = fmaf(1.061405429f, t, -1.453152027f);
  p = fmaf(p, t, 1.421413741f);
  p = fmaf(p, t, -0.284496736f);
  p = fmaf(p, t, 0.254829592f);
  p = p * t;
  float e = __expf(-y*y);
  float erf_y = fmaf(-p, e, 1.0f);
  float s = copysignf(erf_y, v);
  return 0.5f * v * (1.0f + s);
}

using short8  = __attribute__((ext_vector_type(8))) short;
using float4v = __attribute__((ext_vector_type(4))) float;

// ================= bf16 MFMA GEMM =================
// C[M,N](f32) = A[M,K](bf16) @ Bt[N,K](bf16)^T + bias[N](f32)
// MODE 0 plain; MODE 2 split-K over blockIdx.z (chunk Kc, atomicAdd into zeroed C, bias by z==0)
template<int MODE>
__global__ __launch_bounds__(256) void mgemm_k(
    const unsigned short* __restrict__ A, const unsigned short* __restrict__ Bt,
    const float* __restrict__ bias, float* __restrict__ C,
    int M, int N, int K, int Kc)
{
  int klo = 0, khi = K;
  if constexpr (MODE==2){ klo = blockIdx.z*Kc; khi = klo + Kc; }
  __shared__ __align__(16) unsigned short As[128][40];
  __shared__ __align__(16) unsigned short Bs[128][40];
  const int tid  = threadIdx.x;
  const int m0   = blockIdx.y*128, n0 = blockIdx.x*128;
  const int wave = tid>>6, lane = tid&63;
  const int wm   = (wave&1)*64, wn = (wave>>1)*64;
  const int q    = lane>>4, r = lane&15;
  const int sm   = tid>>2, sq = (tid&3)*8;

  float4v acc[4][4];
  #pragma unroll
  for (int i=0;i<4;i++)
    #pragma unroll
    for (int j=0;j<4;j++) acc[i][j] = (float4v){0.f,0.f,0.f,0.f};

  const unsigned short* Ap = A + (long)(m0+sm)*K + sq;
  const unsigned short* Bp = Bt + (long)(n0+sm)*K + sq;
  const long rstep = (long)64*K;

  for (int k0 = klo; k0 < khi; k0 += 32){
    uint4 a0 = *(const uint4*)(Ap + k0);
    uint4 a1 = *(const uint4*)(Ap + k0 + rstep);
    uint4 b0 = *(const uint4*)(Bp + k0);
    uint4 b1 = *(const uint4*)(Bp + k0 + rstep);
    __syncthreads();
    *(uint4*)&As[sm   ][sq] = a0;
    *(uint4*)&As[sm+64][sq] = a1;
    *(uint4*)&Bs[sm   ][sq] = b0;
    *(uint4*)&Bs[sm+64][sq] = b1;
    __syncthreads();
    short8 af[4], bf[4];
    #pragma unroll
    for (int mt=0;mt<4;mt++) af[mt] = *(const short8*)&As[wm + mt*16 + r][q*8];
    #pragma unroll
    for (int nt=0;nt<4;nt++) bf[nt] = *(const short8*)&Bs[wn + nt*16 + r][q*8];
    #pragma unroll
    for (int mt=0;mt<4;mt++)
      #pragma unroll
      for (int nt=0;nt<4;nt++)
        acc[mt][nt] = __builtin_amdgcn_mfma_f32_16x16x32_bf16(af[mt], bf[nt], acc[mt][nt], 0, 0, 0);
  }

  #pragma unroll
  for (int nt=0;nt<4;nt++){
    int col = n0 + wn + nt*16 + r;
    float bb = bias[col];
    #pragma unroll
    for (int mt=0;mt<4;mt++){
      #pragma unroll
      for (int i=0;i<4;i++){
        int row = m0 + wm + mt*16 + q*4 + i;
        if constexpr (MODE==2){
          float v = acc[mt][nt][i];
          if (blockIdx.z == 0) v += bb;
          atomicAdd(&C[(long)row*N + col], v);
        } else {
          C[(long)row*N + col] = acc[mt][nt][i] + bb;
        }
      }
    }
  }
}

// ================= fused liquid + gate-mix + ka-mix + lf-copy -> concat(bf16) ================
// grid (4, 64): n-tile 64 of 256, m-tile 64 of 4096. concat cols: [tok 0:256 | chan 256:512 | moe 512:768 | lf 768:1536]
__global__ __launch_bounds__(256) void liquid_k(
    const unsigned short* __restrict__ xb, const unsigned short* __restrict__ Wdyn_t,
    const float* __restrict__ bt, const float* __restrict__ bc, const float* __restrict__ be,
    const float* __restrict__ gate, const float* __restrict__ ka, const float* __restrict__ lf,
    unsigned short* __restrict__ concat)
{
  __shared__ __align__(16) unsigned short As[64][40];
  __shared__ __align__(16) unsigned short Bs[64][40];
  const int tid = threadIdx.x;
  const int n0 = blockIdx.x*64, m0 = blockIdx.y*64;
  const int wave = tid>>6, lane = tid&63;
  const int wm = (wave&1)*32, wn = (wave>>1)*32;
  const int q = lane>>4, r = lane&15;
  const int sm = tid>>2, sq = (tid&3)*8;

  { // lf segment: rows m0..+63, cols blockIdx.x*192..+191 (f32 -> bf16)
    int row = tid>>2, c0 = blockIdx.x*192 + (tid&3)*48;
    const float* src = lf + (long)(m0+row)*768 + c0;
    unsigned short* dst = concat + (long)(m0+row)*1536 + 768 + c0;
    #pragma unroll
    for (int i=0;i<12;i++){
      float4 v = *(const float4*)(src + i*4);
      ushort4 o; o.x=f2b(v.x); o.y=f2b(v.y); o.z=f2b(v.z); o.w=f2b(v.w);
      *(ushort4*)(dst + i*4) = o;
    }
  }

  float4v moe[2][2];
  #pragma unroll
  for (int i=0;i<2;i++)
    #pragma unroll
    for (int j=0;j<2;j++) moe[i][j] = (float4v){0.f,0.f,0.f,0.f};

  const unsigned short* Ap = xb + (long)(m0+sm)*256 + sq;

  for (int z=0; z<6; z++){
    const unsigned short* Bp = Wdyn_t + (long)z*65536 + (long)(n0+sm)*256 + sq;
    float4v acc[2][2];
    #pragma unroll
    for (int i=0;i<2;i++)
      #pragma unroll
      for (int j=0;j<2;j++) acc[i][j] = (float4v){0.f,0.f,0.f,0.f};
    for (int k0=0; k0<256; k0+=32){
      uint4 a0 = *(const uint4*)(Ap + k0);
      uint4 b0 = *(const uint4*)(Bp + k0);
      __syncthreads();
      *(uint4*)&As[sm][sq] = a0;
      *(uint4*)&Bs[sm][sq] = b0;
      __syncthreads();
      short8 af[2], bf[2];
      #pragma unroll
      for (int mt=0;mt<2;mt++) af[mt] = *(const short8*)&As[wm+mt*16+r][q*8];
      #pragma unroll
      for (int nt=0;nt<2;nt++) bf[nt] = *(const short8*)&Bs[wn+nt*16+r][q*8];
      #pragma unroll
      for (int mt=0;mt<2;mt++)
        #pragma unroll
        for (int nt=0;nt<2;nt++)
          acc[mt][nt] = __builtin_amdgcn_mfma_f32_16x16x32_bf16(af[mt], bf[nt], acc[mt][nt], 0, 0, 0);
    }
    if (z < 2){
      const float* bsrc = z ? bc : bt;
      #pragma unroll
      for (int nt=0;nt<2;nt++){
        int col = n0 + wn + nt*16 + r;
        float bb = bsrc[col];
        #pragma unroll
        for (int mt=0;mt<2;mt++)
          #pragma unroll
          for (int i=0;i<4;i++){
            int row = m0 + wm + mt*16 + q*4 + i;
            concat[(long)row*1536 + z*256 + col] = f2b(acc[mt][nt][i] + bb);
          }
      }
    } else {
      int e = z-2;
      #pragma unroll
      for (int nt=0;nt<2;nt++){
        int col = n0 + wn + nt*16 + r;
        float bb = be[e*256 + col];
        #pragma unroll
        for (int mt=0;mt<2;mt++)
          #pragma unroll
          for (int i=0;i<4;i++){
            int row = m0 + wm + mt*16 + q*4 + i;
            float g = gate[(long)row*5 + e];
            moe[mt][nt][i] = fmaf(g, acc[mt][nt][i] + bb, moe[mt][nt][i]);
          }
      }
    }
  }
  // moe += g4*ka; store
  #pragma unroll
  for (int nt=0;nt<2;nt++){
    int col = n0 + wn + nt*16 + r;
    #pragma unroll
    for (int mt=0;mt<2;mt++)
      #pragma unroll
      for (int i=0;i<4;i++){
        int row = m0 + wm + mt*16 + q*4 + i;
        float g4 = gate[(long)row*5 + 4];
        float v = fmaf(g4, ka[(long)row*256 + col], moe[mt][nt][i]);
        concat[(long)row*1536 + 512 + col] = f2b(v);
      }
  }
}

// ================= psi1 MFMA: h1 += phi(x) @ Wpsi1, phi generated on the fly =================
// BM=64, BN=64, split-K over 16 d-chunks of 16.
__global__ __launch_bounds__(256) void psi1m_k(const float* __restrict__ x,
    const float* __restrict__ Wphi, const float* __restrict__ bphi,
    const unsigned short* __restrict__ Wpsi1_t, float* __restrict__ h1)
{
  __shared__ float xs[64][17];
  __shared__ __align__(16) unsigned int wbls[16][64];
  __shared__ __align__(16) unsigned short As[64][72];
  __shared__ __align__(16) unsigned short Bs[64][72];
  const int tid = threadIdx.x;
  const int m0 = blockIdx.x*64, d_lo = blockIdx.y*16;

  { // stage x: 64 m x 16 d
    int m = tid>>2, off = (tid&3)*4;
    float4 v = *(const float4*)(x + (long)(m0+m)*256 + d_lo + off);
    xs[m][off+0]=v.x; xs[m][off+1]=v.y; xs[m][off+2]=v.z; xs[m][off+3]=v.w;
  }
  { // stage packed Wphi/bphi chunk: 16 d x 64 k
    int rr = tid>>4, cc = (tid&15)*4;
    float4 w4 = *(const float4*)&Wphi[(long)(d_lo+rr)*64 + cc];
    float4 b4 = *(const float4*)&bphi[(long)(d_lo+rr)*64 + cc];
    uint4 p;
    p.x = (unsigned int)f2b(w4.x) | ((unsigned int)f2b(b4.x)<<16);
    p.y = (unsigned int)f2b(w4.y) | ((unsigned int)f2b(b4.y)<<16);
    p.z = (unsigned int)f2b(w4.z) | ((unsigned int)f2b(b4.z)<<16);
    p.w = (unsigned int)f2b(w4.w) | ((unsigned int)f2b(b4.w)<<16);
    *(uint4*)&wbls[rr][cc] = p;
  }
  const int wave = tid>>6, lane = tid&63;
  const int wm = (wave&1)*32, wn = (wave>>1)*32;
  const int q = lane>>4, r = lane&15;
  const int pm = tid>>2, pk = (tid&3)*16;
  const int bn = tid>>2, bk = (tid&3)*16;

  float4v acc[2][2];
  #pragma unroll
  for (int i=0;i<2;i++)
    #pragma unroll
    for (int j=0;j<2;j++) acc[i][j] = (float4v){0.f,0.f,0.f,0.f};

  __syncthreads();

  for (int dd=0; dd<16; dd++){
    int dglob = d_lo + dd;
    const unsigned short* wp = Wpsi1_t + (long)bn*16384 + (long)dglob*64 + bk;
    uint4 b0 = *(const uint4*)wp;
    uint4 b1 = *(const uint4*)(wp + 8);
    float xv = xs[pm][dd];
    ushort4 ph[4];
    #pragma unroll
    for (int kk=0; kk<4; kk++){
      uint4 wb = *(const uint4*)&wbls[dd][pk + kk*4];
      unsigned int u[4] = {wb.x, wb.y, wb.z, wb.w};
      unsigned short o[4];
      #pragma unroll
      for (int e=0;e<4;e++){
        float w = u16tof((unsigned short)(u[e] & 0xffffu));
        float b = u16tof((unsigned short)(u[e] >> 16));
        o[e] = f2b(gelu_f(fmaf(xv, w, b)));
      }
      ph[kk].x=o[0]; ph[kk].y=o[1]; ph[kk].z=o[2]; ph[kk].w=o[3];
    }
    __syncthreads();
    *(uint4*)&Bs[bn][bk]   = b0;
    *(uint4*)&Bs[bn][bk+8] = b1;
    #pragma unroll
    for (int kk=0;kk<4;kk++) *(ushort4*)&As[pm][pk+kk*4] = ph[kk];
    __syncthreads();
    #pragma unroll
    for (int kb=0; kb<2; kb++){
      short8 af[2], bfr[2];
      #pragma unroll
      for (int mt=0;mt<2;mt++) af[mt]  = *(const short8*)&As[wm+mt*16+r][kb*32 + q*8];
      #pragma unroll
      for (int nt=0;nt<2;nt++) bfr[nt] = *(const short8*)&Bs[wn+nt*16+r][kb*32 + q*8];
      #pragma unroll
      for (int mt=0;mt<2;mt++)
        #pragma unroll
        for (int nt=0;nt<2;nt++)
          acc[mt][nt] = __builtin_amdgcn_mfma_f32_16x16x32_bf16(af[mt], bfr[nt], acc[mt][nt], 0, 0, 0);
    }
  }
  #pragma unroll
  for (int nt=0;nt<2;nt++){
    int col = wn + nt*16 + r;
    #pragma unroll
    for (int mt=0;mt<2;mt++)
      #pragma unroll
      for (int i=0;i<4;i++){
        int row = m0 + wm + mt*16 + q*4 + i;
        atomicAdd(&h1[(long)row*64 + col], acc[mt][nt][i]);
      }
  }
}

// ================= prep: x->bf16, W transposes ->bf16 (one kernel) =================
__global__ __launch_bounds__(256) void prep_k(
    const float* __restrict__ x, unsigned short* __restrict__ xb,
    const float* __restrict__ Wres, unsigned short* __restrict__ Wres_t,
    const float* __restrict__ Wo, unsigned short* __restrict__ Wo_t,
    const float* __restrict__ Wpsi1, unsigned short* __restrict__ Wpsi1_t)
{
  __shared__ float t[64][65];
  const int bid = blockIdx.x, tid = threadIdx.x;
  if (bid < 1024){                            // cvt x -> xb
    int i = (bid*256 + tid)*4;
    float4 v = *(const float4*)(x + i);
    ushort4 o; o.x=f2b(v.x); o.y=f2b(v.y); o.z=f2b(v.z); o.w=f2b(v.w);
    *(ushort4*)(xb + i) = o;
    return;
  }
  const float* in; unsigned short* out; int R, C, bx, by;
  if (bid < 1600){ int tt=bid-1024; bx=tt%24; by=tt/24; in=Wres;  out=Wres_t;  R=1536;  C=1536; }
  else if (bid < 1696){ int tt=bid-1600; bx=tt%4; by=tt/4; in=Wo; out=Wo_t;    R=1536;  C=256; }
  else { int tt=bid-1696; bx=0; by=tt; in=Wpsi1; out=Wpsi1_t; R=16384; C=64; }
  const int c0 = bx*64, r0 = by*64;
  const int lr = tid>>2, lc0 = (tid&3)*16;
  #pragma unroll
  for (int i=0;i<4;i++){
    float4 v = *(const float4*)&in[(long)(r0+lr)*C + c0 + lc0 + i*4];
    t[lr][lc0+i*4+0]=v.x; t[lr][lc0+i*4+1]=v.y; t[lr][lc0+i*4+2]=v.z; t[lr][lc0+i*4+3]=v.w;
  }
  __syncthreads();
  const int oc = tid>>2, os = (tid&3)*16;
  #pragma unroll
  for (int i=0;i<16;i++)
    out[(long)(c0+oc)*R + r0 + os + i] = f2b(t[os+i][oc]);
}

// ================= SIMT fp32 GEMM =================
// MODE 0: plain. MODE 3: K-slice per blockIdx.z, write to C+z*sC, NO bias.
// AGELU: A-element transform gelu(a + abias[k]).
__device__ __forceinline__ float4 ld4(const float* p){ return *(const float4*)p; }
__device__ __forceinline__ float4 ld4(const unsigned short* p){
  ushort4 u = *(const ushort4*)p;
  return make_float4(u16tof(u.x), u16tof(u.y), u16tof(u.z), u16tof(u.w));
}
template<typename AT, int MODE, int AGELU>
__global__ __launch_bounds__(256) void gemm_k(
    const AT* __restrict__ A, const float* __restrict__ B, const float* __restrict__ bias,
    const float* __restrict__ abias, float* __restrict__ C,
    int M, int N, int K, int Kc, long sC)
{
  int klo = 0, khi = K;
  if constexpr (MODE==3){ klo = blockIdx.z*Kc; khi = klo + Kc; C += sC*blockIdx.z; }
  __shared__ __align__(16) float As[16][68];
  __shared__ __align__(16) float Bs[16][68];
  const int tid = threadIdx.x;
  const int m0 = blockIdx.y*64, n0 = blockIdx.x*64;
  const int ty = tid>>4, tx = tid&15;
  const int ar = tid>>2, ac = (tid&3)*4;
  const int kr = tid>>4, nc = (tid&15)*4;
  float acc[4][4] = {};
  const AT* Ap = A + (long)(m0+ar)*K;

  for (int k0 = klo; k0 < khi; k0 += 16){
    float4 av = ld4(Ap + k0 + ac);
    if constexpr (AGELU){
      float4 ab = *(const float4*)(abias + k0 + ac);
      av.x = gelu_f(av.x + ab.x); av.y = gelu_f(av.y + ab.y);
      av.z = gelu_f(av.z + ab.z); av.w = gelu_f(av.w + ab.w);
    }
    float4 bv = *(const float4*)(B + (long)(k0+kr)*N + (n0+nc));
    __syncthreads();
    As[ac+0][ar] = av.x; As[ac+1][ar] = av.y; As[ac+2][ar] = av.z; As[ac+3][ar] = av.w;
    *(float4*)&Bs[kr][nc] = bv;
    __syncthreads();
    #pragma unroll
    for (int k = 0; k < 16; k++){
      float4 a4 = *(const float4*)&As[k][ty*4];
      float4 b4 = *(const float4*)&Bs[k][tx*4];
      float a[4] = {a4.x,a4.y,a4.z,a4.w};
      float b[4] = {b4.x,b4.y,b4.z,b4.w};
      #pragma unroll
      for (int i = 0; i < 4; i++)
        #pragma unroll
        for (int j = 0; j < 4; j++)
          acc[i][j] = fmaf(a[i], b[j], acc[i][j]);
    }
  }
  float bv4[4] = {0.f,0.f,0.f,0.f};
  if constexpr (MODE!=3){
    #pragma unroll
    for (int j = 0; j < 4; j++) bv4[j] = bias[n0 + tx*4 + j];
  }
  #pragma unroll
  for (int i = 0; i < 4; i++){
    long row = m0 + ty*4 + i;
    #pragma unroll
    for (int j = 0; j < 4; j++)
      C[row*(long)N + n0 + tx*4 + j] = acc[i][j] + bv4[j];
  }
}

// ---------- adapt GEMM + column-sum atomics (for am) ----------
__global__ __launch_bounds__(256) void adapt_k(const float* __restrict__ A, const float* __restrict__ B,
    const float* __restrict__ bias, float* __restrict__ C, float* __restrict__ amraw)
{
  const int K = 256, N = 128;
  __shared__ __align__(16) float As[16][68];
  __shared__ __align__(16) float Bs[16][68];
  const int tid = threadIdx.x;
  const int m0 = blockIdx.y*64, n0 = blockIdx.x*64;
  const int ty = tid>>4, tx = tid&15;
  const int ar = tid>>2, ac = (tid&3)*4;
  const int kr = tid>>4, nc = (tid&15)*4;
  float acc[4][4] = {};
  const float* Ap = A + (long)(m0+ar)*K;
  for (int k0 = 0; k0 < K; k0 += 16){
    float4 av = *(const float4*)(Ap + k0 + ac);
    float4 bv = *(const float4*)(B + (long)(k0+kr)*N + (n0+nc));
    __syncthreads();
    As[ac+0][ar] = av.x; As[ac+1][ar] = av.y; As[ac+2][ar] = av.z; As[ac+3][ar] = av.w;
    *(float4*)&Bs[kr][nc] = bv;
    __syncthreads();
    #pragma unroll
    for (int k = 0; k < 16; k++){
      float4 a4 = *(const float4*)&As[k][ty*4];
      float4 b4 = *(const float4*)&Bs[k][tx*4];
      float a[4] = {a4.x,a4.y,a4.z,a4.w};
      float b[4] = {b4.x,b4.y,b4.z,b4.w};
      #pragma unroll
      for (int i = 0; i < 4; i++)
        #pragma unroll
        for (int j = 0; j < 4; j++)
          acc[i][j] = fmaf(a[i], b[j], acc[i][j]);
    }
  }
  float colsum[4] = {};
  #pragma unroll
  for (int j = 0; j < 4; j++){
    float bb = bias[n0 + tx*4 + j];
    #pragma unroll
    for (int i = 0; i < 4; i++){
      float v = acc[i][j] + bb;
      C[(long)(m0 + ty*4 + i)*N + n0 + tx*4 + j] = v;
      colsum[j] += v;
    }
  }
  #pragma unroll
  for (int j = 0; j < 4; j++) atomicAdd(&amraw[n0 + tx*4 + j], colsum[j]);
}

// ---------- gate = softmax(adapt @ Wg + bg) ----------
__global__ __launch_bounds__(256) void gate_k(const float* __restrict__ adapt,
    const float* __restrict__ Wg, const float* __restrict__ bg, float* __restrict__ gate){
  __shared__ float wg[640]; __shared__ float bgs[5];
  int tid = threadIdx.x;
  for (int i = tid; i < 640; i += 256) wg[i] = Wg[i];
  if (tid < 5) bgs[tid] = bg[tid];
  __syncthreads();
  int n = blockIdx.x*256 + tid;
  float l[5] = {bgs[0],bgs[1],bgs[2],bgs[3],bgs[4]};
  const float* ar = adapt + (long)n*128;
  for (int a = 0; a < 128; a++){
    float av = ar[a];
    #pragma unroll
    for (int e = 0; e < 5; e++) l[e] = fmaf(av, wg[a*5+e], l[e]);
  }
  float mx = l[0];
  #pragma unroll
  for (int e = 1; e < 5; e++) mx = fmaxf(mx, l[e]);
  float sum = 0.f;
  #pragma unroll
  for (int e = 0; e < 5; e++){ l[e] = expf(l[e]-mx); sum += l[e]; }
  float inv = 1.0f/sum;
  #pragma unroll
  for (int e = 0; e < 5; e++) gate[(long)n*5+e] = l[e]*inv;
}

// ---------- dynamic weights -> bf16 TRANSPOSED: Wdyn_t[z][out][in] (float4 per thread) ----------
__global__ __launch_bounds__(256) void dynw_k(const float* __restrict__ am,
    const float* Wt, const float* Wt_a, const float* bt_a,
    const float* Wc, const float* Wc_a, const float* bc_a,
    const float* We, const float* We_a, const float* be_a,
    unsigned short* __restrict__ Wdyn_t)
{
  __shared__ float ams[128];
  int tid = threadIdx.x;
  if (tid < 128) ams[tid] = am[tid] * (1.0f/4096.0f);
  __syncthreads();
  long g4 = ((long)blockIdx.x*256 + tid)*4;     // 0 .. 6*65536-4
  int seg = (int)(g4 >> 16); int m = (int)(g4 & 65535);
  const float *W, *Wa, *ba;
  if (seg == 0){ W = Wt; Wa = Wt_a; ba = bt_a; }
  else if (seg == 1){ W = Wc; Wa = Wc_a; ba = bc_a; }
  else { int e = seg-2; W = We + (long)e*65536; Wa = We_a + (long)e*65536*128; ba = be_a + (long)e*65536; }
  float4 s = *(const float4*)&W[m];
  float4 bb = *(const float4*)&ba[m];
  s.x += bb.x; s.y += bb.y; s.z += bb.z; s.w += bb.w;
  for (int a = 0; a < 128; a++){
    float av = ams[a];
    float4 wa = *(const float4*)&Wa[(long)a*65536 + m];
    s.x = fmaf(av, wa.x, s.x); s.y = fmaf(av, wa.y, s.y);
    s.z = fmaf(av, wa.z, s.z); s.w = fmaf(av, wa.w, s.w);
  }
  int row = m >> 8, col = m & 255;
  unsigned short* o = Wdyn_t + (long)seg*65536 + (long)col*256 + row;
  o[0]   = f2b(s.x);
  o[256] = f2b(s.y);
  o[512] = f2b(s.z);
  o[768] = f2b(s.w);
}

// ---------- fused cw(softmax) + combine ----------
__global__ __launch_bounds__(256) void combine2_k(const float* __restrict__ hpre,
    const float* __restrict__ b1, const float* __restrict__ W2, const float* __restrict__ b2,
    const float* __restrict__ residual, unsigned short* __restrict__ concat)
{
  __shared__ float red[64][4];
  __shared__ float lv[4];
  __shared__ float cws[4];
  int n = blockIdx.x, tid = threadIdx.x;
  if (tid < 64){
    float s = b1[tid];
    #pragma unroll
    for (int z=0; z<8; z++) s += hpre[(long)z*262144 + (long)n*64 + tid];
    float hj = gelu_f(s);
    float4 w = *(const float4*)&W2[tid*4];
    red[tid][0]=hj*w.x; red[tid][1]=hj*w.y; red[tid][2]=hj*w.z; red[tid][3]=hj*w.w;
  }
  __syncthreads();
  if (tid < 4){
    float l = b2[tid];
    for (int j=0;j<64;j++) l += red[j][tid];
    lv[tid] = l;
  }
  __syncthreads();
  if (tid == 0){
    float mx = fmaxf(fmaxf(lv[0],lv[1]), fmaxf(lv[2],lv[3]));
    float e0=expf(lv[0]-mx), e1=expf(lv[1]-mx), e2=expf(lv[2]-mx), e3=expf(lv[3]-mx);
    float inv = 1.0f/(e0+e1+e2+e3);
    cws[0]=e0*inv; cws[1]=e1*inv; cws[2]=e2*inv; cws[3]=e3*inv;
  }
  __syncthreads();
  #pragma unroll
  for (int it=0; it<6; it++){
    int j = tid + it*256;
    int seg = (j < 768) ? (j >> 8) : 3;
    long idx = (long)n*1536 + j;
    float v = fmaf(cws[seg], u16tof(concat[idx]), residual[idx]);
    concat[idx] = f2b(v);
  }
}

// ---------- launch ----------
extern "C" void kernel_launch(void* const* d_in, const int* in_sizes, int n_in,
                              void* d_out, int out_size, void* d_ws, size_t ws_size,
                              hipStream_t stream)
{
  const float* x      = (const float*)d_in[0];
  const float* lf     = (const float*)d_in[1];
  const float* W_feat = (const float*)d_in[2];
  const float* b_feat = (const float*)d_in[3];
  const float* Wt     = (const float*)d_in[4];
  const float* bt     = (const float*)d_in[5];
  const float* Wt_a   = (const float*)d_in[6];
  const float* bt_a   = (const float*)d_in[7];
  const float* Wc     = (const float*)d_in[8];
  const float* bc     = (const float*)d_in[9];
  const float* Wc_a   = (const float*)d_in[10];
  const float* bc_a   = (const float*)d_in[11];
  const float* We     = (const float*)d_in[12];
  const float* be     = (const float*)d_in[13];
  const float* We_a   = (const float*)d_in[14];
  const float* be_a   = (const float*)d_in[15];
  const float* Wg     = (const float*)d_in[16];
  const float* bg     = (const float*)d_in[17];
  const float* Wphi   = (const float*)d_in[18];
  const float* bphi   = (const float*)d_in[19];
  const float* Wpsi1  = (const float*)d_in[20];
  const float* bpsi1  = (const float*)d_in[21];
  const float* Wpsi2  = (const float*)d_in[22];
  const float* bpsi2  = (const float*)d_in[23];
  const float* Wres   = (const float*)d_in[24];
  const float* bres   = (const float*)d_in[25];
  const float* W1     = (const float*)d_in[26];
  const float* b1     = (const float*)d_in[27];
  const float* W2     = (const float*)d_in[28];
  const float* b2     = (const float*)d_in[29];
  const float* Wo     = (const float*)d_in[30];
  const float* bo     = (const float*)d_in[31];

  float* ws = (float*)d_ws;
  float* am       = ws;                        // 128   (zeroed with h1)
  float* h1       = ws + 128;                  // 262,144
  float* adapt    = ws + 262272;               // 524,288
  float* gate     = adapt + 524288;            // 20,480
  float* ka       = gate + 20480;              // 1,048,576
  float* residual = ka + 1048576;              // 6,291,456
  float* hpre     = residual + 6291456;        // 8 x 262,144
  unsigned short* xb      = (unsigned short*)(hpre + 2097152);  // 1,048,576 u16
  unsigned short* Wdyn_t  = xb + 1048576;                       // 393,216
  unsigned short* Wres_t  = Wdyn_t + 393216;                    // 2,359,296
  unsigned short* Wo_t    = Wres_t + 2359296;                   // 393,216
  unsigned short* Wpsi1_t = Wo_t + 393216;                      // 1,048,576
  unsigned short* concat  = Wpsi1_t + 1048576;                  // 6,291,456  (~61 MB total)

  dim3 b256(256);

  hipMemsetAsync(ws, 0, (128 + 262144)*sizeof(float), stream);          // am + h1
  prep_k<<<dim3(1952), b256, 0, stream>>>(x, xb, Wres, Wres_t, Wo, Wo_t, Wpsi1, Wpsi1_t);

  // adapt = x @ W_feat + b_feat, + column-sum into am
  adapt_k<<<dim3(2,64), b256, 0, stream>>>(x, W_feat, b_feat, adapt, am);
  gate_k<<<dim3(16), b256, 0, stream>>>(adapt, Wg, bg, gate);
  dynw_k<<<dim3(384), b256, 0, stream>>>(am, Wt,Wt_a,bt_a, Wc,Wc_a,bc_a, We,We_a,be_a, Wdyn_t);

  // KA expert: psi1 fused-phi MFMA (16 split-K chunks, atomics into zeroed h1)
  psi1m_k<<<dim3(64,16), b256, 0, stream>>>(x, Wphi, bphi, Wpsi1_t, h1);
  // ka = gelu(h1 + bpsi1) @ Wpsi2 + bpsi2 (gelu folded into A-load)
  gemm_k<float,0,1><<<dim3(4,64), b256, 0, stream>>>(h1, Wpsi2, bpsi2, bpsi1, ka, 4096,256,64, 0,0);

  // fused liquid GEMMs + gate-mix + ka-mix + lf-copy -> concat (bf16)
  liquid_k<<<dim3(4,64), b256, 0, stream>>>(xb, Wdyn_t, bt, bc, be, gate, ka, lf, concat);

  // residual = concat @ Wres + bres   MFMA
  mgemm_k<0><<<dim3(12,32), b256, 0, stream>>>(concat, Wres_t, bres, residual, 4096,1536,1536, 0);

  // h_pre slices = concat @ W1 (8 K-slices, no bias; summed in combine2)
  gemm_k<unsigned short,3,0><<<dim3(1,64,8), b256, 0, stream>>>(concat, W1, nullptr, nullptr, hpre, 4096,64,1536, 192, 262144);

  // cw softmax + combine (in-place on concat)
  combine2_k<<<dim3(4096), b256, 0, stream>>>(hpre, b1, W2, b2, residual, concat);

  // out = combined @ Wo + bo   MFMA split-K=4 into zeroed d_out
  hipMemsetAsync(d_out, 0, (size_t)out_size*sizeof(float), stream);
  mgemm_k<2><<<dim3(2,32,4), b256, 0, stream>>>(concat, Wo_t, bo, (float*)d_out, 4096,256,1536, 384);
}